// Round 2
// baseline (1394.716 us; speedup 1.0000x reference)
//
#include <hip/hip_runtime.h>

typedef __bf16 bf16;
typedef __bf16 bf16x8 __attribute__((ext_vector_type(8)));
typedef __bf16 bf16x4 __attribute__((ext_vector_type(4)));
typedef float  f32x4  __attribute__((ext_vector_type(4)));

#define MFMA16(a, b, c) __builtin_amdgcn_mfma_f32_16x16x32_bf16(a, b, c, 0, 0, 0)

__device__ __forceinline__ void gload_lds16(const void* g, void* l) {
    __builtin_amdgcn_global_load_lds((const __attribute__((address_space(1))) void*)g,
                                     (__attribute__((address_space(3))) void*)l, 16, 0, 0);
}

// window-order row -> original-order row (inverse of roll(-4,-4)+partition)
__device__ __forceinline__ long win2orig(long r) {
    long b = r >> 12; int rem = (int)(r & 4095);
    int widx = rem >> 6, t = rem & 63;
    int rp = ((widx >> 3) << 3) + (t >> 3), cp = ((widx & 7) << 3) + (t & 7);
    int rr = (rp + 4) & 63, cc = (cp + 4) & 63;
    return (b << 12) + rr * 64 + cc;
}

// ---------------------------------------------------------------- GEMM
// C[M,N] = A[M,K] (bf16) * Bt[N,K]^T (bf16) + bias, optional gelu.
// m97 structure: 128x128 tile, BK=32, global_load_lds w=16, fragment-linear LDS.
template <int GELU>
__global__ __launch_bounds__(256) void gemm_bt(const bf16* __restrict__ A,
                                               const bf16* __restrict__ Bt,
                                               const float* __restrict__ bias,
                                               bf16* __restrict__ C,
                                               int M, int N, int K) {
    __shared__ bf16 As[4096];
    __shared__ bf16 Bs[4096];
    const int t = threadIdx.x;
    const int w = t >> 6, l = t & 63;
    const int l15 = l & 15, q4 = l >> 4;
    const int wm = w >> 1, wn = w & 1;
    const long row0 = (long)blockIdx.y * 128;
    const int col0 = blockIdx.x * 128;

    const bf16* aP = A + (row0 + w * 16 + l15) * (long)K + q4 * 8;
    const bf16* bP = Bt + (long)(col0 + w * 16 + l15) * K + q4 * 8;
    const long step64 = 64L * K;

    f32x4 acc[4][4];
#pragma unroll
    for (int i = 0; i < 4; i++)
#pragma unroll
        for (int j = 0; j < 4; j++)
#pragma unroll
            for (int r = 0; r < 4; r++) acc[i][j][r] = 0.f;

    const int KT = K >> 5;
    for (int kt = 0; kt < KT; ++kt) {
        __syncthreads();
        gload_lds16(aP,          &As[w * 512]);
        gload_lds16(aP + step64, &As[w * 512 + 2048]);
        gload_lds16(bP,          &Bs[w * 512]);
        gload_lds16(bP + step64, &Bs[w * 512 + 2048]);
        aP += 32; bP += 32;
        __syncthreads();
        bf16x8 af[4], bfv[4];
#pragma unroll
        for (int mi = 0; mi < 4; mi++) af[mi] = *(const bf16x8*)(&As[(wm * 4 + mi) * 512 + l * 8]);
#pragma unroll
        for (int nj = 0; nj < 4; nj++) bfv[nj] = *(const bf16x8*)(&Bs[(wn * 4 + nj) * 512 + l * 8]);
#pragma unroll
        for (int mi = 0; mi < 4; mi++)
#pragma unroll
            for (int nj = 0; nj < 4; nj++) acc[mi][nj] = MFMA16(af[mi], bfv[nj], acc[mi][nj]);
    }

    float cb[4];
#pragma unroll
    for (int nj = 0; nj < 4; nj++) cb[nj] = bias[col0 + wn * 64 + nj * 16 + l15];

#pragma unroll
    for (int mi = 0; mi < 4; mi++) {
#pragma unroll
        for (int reg = 0; reg < 4; reg++) {
            long r = row0 + wm * 64 + mi * 16 + q4 * 4 + reg;
            bf16* cpn = C + r * (long)N + col0 + wn * 64 + l15;
#pragma unroll
            for (int nj = 0; nj < 4; nj++) {
                float v = acc[mi][nj][reg] + cb[nj];
                if (GELU) {  // tanh gelu (jax.nn.gelu approximate=True)
                    float u = 0.7978845608028654f * (v + 0.044715f * v * v * v);
                    float e = __expf(2.f * u);
                    float th = 1.f - 2.f / (e + 1.f);
                    v = 0.5f * v * (1.f + th);
                }
                cpn[nj * 16] = (bf16)v;
            }
        }
    }
}

// ---------------------------------------------------------------- attention
// One wave per (window, head). qkv rows in window order (chunk-local).
__global__ __launch_bounds__(64) void attn_kernel(const bf16* __restrict__ qkv,
                                                  const float* __restrict__ bias16,
                                                  const float* __restrict__ logit_scale,
                                                  bf16* __restrict__ outp) {
    __shared__ bf16 P[64 * 72];
    __shared__ bf16 Vt[32 * 72];
    const int unit = blockIdx.x;
    const int w = unit >> 3, h = unit & 7;
    const int l = threadIdx.x;
    const int l15 = l & 15, q4 = l >> 4;
    const bf16* base = qkv + (long)w * 64 * 768;

    {  // stage V^T: lane l holds token l
        const bf16* vp = base + l * 768 + 512 + h * 32;
#pragma unroll
        for (int c = 0; c < 4; c++) {
            bf16x8 vv = *(const bf16x8*)(vp + c * 8);
#pragma unroll
            for (int j = 0; j < 8; j++) Vt[(c * 8 + j) * 72 + l] = vv[j];
        }
    }

    const float scale = __expf(fminf(logit_scale[h], 4.605170186f));

    bf16x8 qf[4], kf[4];
#pragma unroll
    for (int mi = 0; mi < 4; mi++) {  // l2-normalized Q fragments
        const bf16* p = base + (mi * 16 + l15) * 768 + h * 32 + q4 * 8;
        bf16x8 xv = *(const bf16x8*)p;
        float fv[8]; float ss = 0.f;
#pragma unroll
        for (int j = 0; j < 8; j++) { fv[j] = (float)xv[j]; ss += fv[j] * fv[j]; }
        ss += __shfl_xor(ss, 16); ss += __shfl_xor(ss, 32);
        float rs = rsqrtf(fmaxf(ss, 1e-12f));
#pragma unroll
        for (int j = 0; j < 8; j++) qf[mi][j] = (bf16)(fv[j] * rs);
    }
#pragma unroll
    for (int nj = 0; nj < 4; nj++) {  // l2-normalized K fragments
        const bf16* p = base + (nj * 16 + l15) * 768 + 256 + h * 32 + q4 * 8;
        bf16x8 xv = *(const bf16x8*)p;
        float fv[8]; float ss = 0.f;
#pragma unroll
        for (int j = 0; j < 8; j++) { fv[j] = (float)xv[j]; ss += fv[j] * fv[j]; }
        ss += __shfl_xor(ss, 16); ss += __shfl_xor(ss, 32);
        float rs = rsqrtf(fmaxf(ss, 1e-12f));
#pragma unroll
        for (int j = 0; j < 8; j++) kf[nj][j] = (bf16)(fv[j] * rs);
    }

    f32x4 acc[4][4];
#pragma unroll
    for (int i = 0; i < 4; i++)
#pragma unroll
        for (int j = 0; j < 4; j++)
#pragma unroll
            for (int r = 0; r < 4; r++) acc[i][j][r] = 0.f;
#pragma unroll
    for (int mi = 0; mi < 4; mi++)
#pragma unroll
        for (int nj = 0; nj < 4; nj++) acc[mi][nj] = MFMA16(qf[mi], kf[nj], acc[mi][nj]);

    // scale + CPB bias + shift mask  (mask regions use unshifted window coords, per ref)
    const int widx = w & 63, wr = widx >> 3, wc = widx & 7;
    const bool edge = (wr == 7) || (wc == 7);
    int crid[4];
    if (edge) {
#pragma unroll
        for (int nj = 0; nj < 4; nj++) {
            int m = nj * 16 + l15;
            int R = wr * 8 + (m >> 3), Cc = wc * 8 + (m & 7);
            crid[nj] = ((R < 56) ? 0 : (R < 60 ? 1 : 2)) * 3 + ((Cc < 56) ? 0 : (Cc < 60 ? 1 : 2));
        }
    }
    const float* bh = bias16 + h * 4096;
#pragma unroll
    for (int mi = 0; mi < 4; mi++) {
#pragma unroll
        for (int reg = 0; reg < 4; reg++) {
            int n = mi * 16 + q4 * 4 + reg;
            const float* bp = bh + n * 64;
            int nrid = 0;
            if (edge) {
                int R = wr * 8 + (n >> 3), Cc = wc * 8 + (n & 7);
                nrid = ((R < 56) ? 0 : (R < 60 ? 1 : 2)) * 3 + ((Cc < 56) ? 0 : (Cc < 60 ? 1 : 2));
            }
#pragma unroll
            for (int nj = 0; nj < 4; nj++) {
                float v = acc[mi][nj][reg] * scale + bp[nj * 16 + l15];
                if (edge && nrid != crid[nj]) v -= 100.f;
                acc[mi][nj][reg] = v;
            }
        }
    }

    // row softmax (row = 16 lanes sharing q4, across 4 nj regs)
#pragma unroll
    for (int mi = 0; mi < 4; mi++) {
#pragma unroll
        for (int reg = 0; reg < 4; reg++) {
            float mx = fmaxf(fmaxf(acc[mi][0][reg], acc[mi][1][reg]),
                             fmaxf(acc[mi][2][reg], acc[mi][3][reg]));
            mx = fmaxf(mx, __shfl_xor(mx, 1));
            mx = fmaxf(mx, __shfl_xor(mx, 2));
            mx = fmaxf(mx, __shfl_xor(mx, 4));
            mx = fmaxf(mx, __shfl_xor(mx, 8));
            float s = 0.f;
#pragma unroll
            for (int nj = 0; nj < 4; nj++) {
                float e = __expf(acc[mi][nj][reg] - mx);
                acc[mi][nj][reg] = e; s += e;
            }
            s += __shfl_xor(s, 1); s += __shfl_xor(s, 2);
            s += __shfl_xor(s, 4); s += __shfl_xor(s, 8);
            float inv = 1.f / s;
            int n = mi * 16 + q4 * 4 + reg;
#pragma unroll
            for (int nj = 0; nj < 4; nj++)
                P[n * 72 + nj * 16 + l15] = (bf16)(acc[mi][nj][reg] * inv);
        }
    }
    __syncthreads();

    // O = P @ V  (K=64 in two 32-steps)
    f32x4 o[4][2];
#pragma unroll
    for (int i = 0; i < 4; i++)
#pragma unroll
        for (int j = 0; j < 2; j++)
#pragma unroll
            for (int r = 0; r < 4; r++) o[i][j][r] = 0.f;
#pragma unroll
    for (int ks = 0; ks < 2; ks++) {
        bf16x8 vf[2];
#pragma unroll
        for (int nj = 0; nj < 2; nj++) vf[nj] = *(const bf16x8*)(&Vt[(nj * 16 + l15) * 72 + ks * 32 + q4 * 8]);
#pragma unroll
        for (int mi = 0; mi < 4; mi++) {
            bf16x8 pf = *(const bf16x8*)(&P[(mi * 16 + l15) * 72 + ks * 32 + q4 * 8]);
#pragma unroll
            for (int nj = 0; nj < 2; nj++) o[mi][nj] = MFMA16(pf, vf[nj], o[mi][nj]);
        }
    }

    bf16* op = outp + (long)w * 64 * 256 + h * 32;
#pragma unroll
    for (int mi = 0; mi < 4; mi++)
#pragma unroll
        for (int reg = 0; reg < 4; reg++) {
            int tok = mi * 16 + q4 * 4 + reg;
#pragma unroll
            for (int nj = 0; nj < 2; nj++)
                op[tok * 256 + nj * 16 + l15] = (bf16)o[mi][nj][reg];
        }
}

// ---------------------------------------------------------------- norms
// norm1: chunk rows in window order; scatter to orig order: x1 = x + LN(proj_out)
__global__ __launch_bounds__(256) void norm1_kernel(const bf16* __restrict__ pin,
                                                    const float* __restrict__ x,
                                                    const float* __restrict__ g,
                                                    const float* __restrict__ bb,
                                                    bf16* __restrict__ x1h,
                                                    long base) {
    const int tid = threadIdx.x;
    const int wid = tid >> 6, l = tid & 63;
    const long rl = (long)blockIdx.x * 4 + wid;
    bf16x4 v4 = *(const bf16x4*)(pin + rl * 256 + l * 4);
    float v[4]; float s = 0.f, sq = 0.f;
#pragma unroll
    for (int c = 0; c < 4; c++) { v[c] = (float)v4[c]; s += v[c]; sq += v[c] * v[c]; }
#pragma unroll
    for (int off = 1; off < 64; off <<= 1) { s += __shfl_xor(s, off); sq += __shfl_xor(sq, off); }
    float mu = s * 0.00390625f;
    float var = sq * 0.00390625f - mu * mu;
    float rstd = rsqrtf(var + 1e-6f);
    long orig = win2orig(base + rl);
    float4 xv = *(const float4*)(x + orig * 256 + l * 4);
    float4 gv = *(const float4*)(g + l * 4);
    float4 bv = *(const float4*)(bb + l * 4);
    bf16x4 oh;
    oh[0] = (bf16)(xv.x + ((v[0] - mu) * rstd * gv.x + bv.x));
    oh[1] = (bf16)(xv.y + ((v[1] - mu) * rstd * gv.y + bv.y));
    oh[2] = (bf16)(xv.z + ((v[2] - mu) * rstd * gv.z + bv.z));
    oh[3] = (bf16)(xv.w + ((v[3] - mu) * rstd * gv.w + bv.w));
    *(bf16x4*)(x1h + orig * 256 + l * 4) = oh;
}

// norm2: out = x1 + LN(fc2_out), all in orig order, chunk rows contiguous
__global__ __launch_bounds__(256) void norm2_kernel(const bf16* __restrict__ hin,
                                                    const bf16* __restrict__ x1h,
                                                    const float* __restrict__ g,
                                                    const float* __restrict__ bb,
                                                    float* __restrict__ outp,
                                                    long base) {
    const int tid = threadIdx.x;
    const int wid = tid >> 6, l = tid & 63;
    const long rl = (long)blockIdx.x * 4 + wid;
    bf16x4 v4 = *(const bf16x4*)(hin + rl * 256 + l * 4);
    float v[4]; float s = 0.f, sq = 0.f;
#pragma unroll
    for (int c = 0; c < 4; c++) { v[c] = (float)v4[c]; s += v[c]; sq += v[c] * v[c]; }
#pragma unroll
    for (int off = 1; off < 64; off <<= 1) { s += __shfl_xor(s, off); sq += __shfl_xor(sq, off); }
    float mu = s * 0.00390625f;
    float var = sq * 0.00390625f - mu * mu;
    float rstd = rsqrtf(var + 1e-6f);
    const long rg = base + rl;
    bf16x4 xv4 = *(const bf16x4*)(x1h + rg * 256 + l * 4);
    float4 gv = *(const float4*)(g + l * 4);
    float4 bv = *(const float4*)(bb + l * 4);
    float4 ov;
    ov.x = (float)xv4[0] + ((v[0] - mu) * rstd * gv.x + bv.x);
    ov.y = (float)xv4[1] + ((v[1] - mu) * rstd * gv.y + bv.y);
    ov.z = (float)xv4[2] + ((v[2] - mu) * rstd * gv.z + bv.z);
    ov.w = (float)xv4[3] + ((v[3] - mu) * rstd * gv.w + bv.w);
    *(float4*)(outp + rg * 256 + l * 4) = ov;
}

// ---------------------------------------------------------------- small prep
// gather chunk rows (window order) from x (orig order, fp32), cast to bf16
__global__ __launch_bounds__(256) void gather_cast(const float* __restrict__ x,
                                                   bf16* __restrict__ out, long base) {
    const int tid = threadIdx.x;
    const int wid = tid >> 6, l = tid & 63;
    const long rl = (long)blockIdx.x * 4 + wid;
    long orig = win2orig(base + rl);
    float4 v = *(const float4*)(x + orig * 256 + l * 4);
    bf16x4 o = {(bf16)v.x, (bf16)v.y, (bf16)v.z, (bf16)v.w};
    *(bf16x4*)(out + rl * 256 + l * 4) = o;
}

// out[N,K] = cast(in[K,N]^T)
__global__ void transpose_cast(const float* __restrict__ in, bf16* __restrict__ out, int K, int N) {
    int id = blockIdx.x * 256 + threadIdx.x;
    if (id < K * N) {
        int n = id / K, k = id - n * K;
        out[id] = (bf16)in[k * N + n];
    }
}

__global__ void build_qkv_bias(const float* __restrict__ qb, const float* __restrict__ vb,
                               float* __restrict__ out) {
    int i = blockIdx.x * 256 + threadIdx.x;
    if (i < 768) out[i] = (i < 256) ? qb[i] : ((i < 512) ? 0.f : vb[i - 512]);
}

__device__ __forceinline__ float cpcoord(int d) {
    float v = (float)d * (8.0f / 7.0f);
    float r = log2f(fabsf(v) + 1.0f) * (1.0f / 3.0f);
    return v < 0.f ? -r : r;
}

__global__ void cpb1(const float* __restrict__ w1, const float* __restrict__ b1,
                     const float* __restrict__ w2, float* __restrict__ tbl) {
    int a = threadIdx.x;
    if (a >= 225) return;
    int i = a / 15, j = a - i * 15;
    float t0 = cpcoord(i - 7), t1 = cpcoord(j - 7);
    float acc[8];
#pragma unroll
    for (int o = 0; o < 8; o++) acc[o] = 0.f;
    for (int jj = 0; jj < 512; jj++) {
        float hv = fmaf(t0, w1[jj], fmaf(t1, w1[512 + jj], b1[jj]));
        hv = fmaxf(hv, 0.f);
#pragma unroll
        for (int o = 0; o < 8; o++) acc[o] = fmaf(hv, w2[jj * 8 + o], acc[o]);
    }
#pragma unroll
    for (int o = 0; o < 8; o++) tbl[a * 8 + o] = acc[o];
}

__global__ void cpb2(const float* __restrict__ tbl, float* __restrict__ bias16) {
    int id = blockIdx.x * 256 + threadIdx.x;
    if (id >= 32768) return;
    int h = id >> 12, n = (id >> 6) & 63, m = id & 63;
    int r0 = (n >> 3) - (m >> 3) + 7;
    int r1 = (n & 7) - (m & 7) + 7;
    float v = tbl[(r0 * 15 + r1) * 8 + h];
    bias16[id] = 16.f / (1.f + __expf(-v));
}

// ---------------------------------------------------------------- launch
extern "C" void kernel_launch(void* const* d_in, const int* in_sizes, int n_in,
                              void* d_out, int out_size, void* d_ws, size_t ws_size,
                              hipStream_t stream) {
    const float* x   = (const float*)d_in[0];
    const float* qkvw= (const float*)d_in[1];
    const float* qb  = (const float*)d_in[2];
    const float* vb  = (const float*)d_in[3];
    const float* ls  = (const float*)d_in[4];
    const float* cw1 = (const float*)d_in[5];
    const float* cb1 = (const float*)d_in[6];
    const float* cw2 = (const float*)d_in[7];
    const float* pw  = (const float*)d_in[8];
    const float* pb  = (const float*)d_in[9];
    const float* n1s = (const float*)d_in[10];
    const float* n1b = (const float*)d_in[11];
    const float* n2s = (const float*)d_in[12];
    const float* n2b = (const float*)d_in[13];
    const float* f1w = (const float*)d_in[14];
    const float* f1b = (const float*)d_in[15];
    const float* f2w = (const float*)d_in[16];
    const float* f2b = (const float*)d_in[17];

    char* ws = (char*)d_ws;
    if (ws_size < 119537664UL) return;  // peak scratch = 114 MiB
    bf16*  qkvBt   = (bf16*)(ws + 0);
    bf16*  projBt  = (bf16*)(ws + 393216);
    bf16*  fc1Bt   = (bf16*)(ws + 524288);
    bf16*  fc2Bt   = (bf16*)(ws + 1048576);
    float* qkvBias = (float*)(ws + 1572864);
    float* cpbTbl  = (float*)(ws + 1575936);
    float* bias16  = (float*)(ws + 1583360);
    bf16*  x1h     = (bf16*)(ws + 2097152);   // 131072x256 bf16 (orig order)
    char*  pool    = ws + 69206016;           // 48 MiB overlay pool
    bf16*  xbfC  = (bf16*)(pool + 0);          // 16384x256
    bf16*  qkvC  = (bf16*)(pool + 8388608);    // 16384x768
    bf16*  attnC = (bf16*)(pool + 33554432);   // 16384x256
    bf16*  projC = (bf16*)(pool + 41943040);   // 16384x256
    bf16*  hC    = (bf16*)(pool + 0);          // 16384x1024 (MLP stage)
    bf16*  fc2C  = (bf16*)(pool + 33554432);   // 16384x256  (MLP stage)

    transpose_cast<<<768, 256, 0, stream>>>(qkvw, qkvBt, 256, 768);
    transpose_cast<<<256, 256, 0, stream>>>(pw, projBt, 256, 256);
    transpose_cast<<<1024, 256, 0, stream>>>(f1w, fc1Bt, 256, 1024);
    transpose_cast<<<1024, 256, 0, stream>>>(f2w, fc2Bt, 1024, 256);
    build_qkv_bias<<<3, 256, 0, stream>>>(qb, vb, qkvBias);
    cpb1<<<1, 256, 0, stream>>>(cw1, cb1, cw2, cpbTbl);
    cpb2<<<128, 256, 0, stream>>>(cpbTbl, bias16);

    // attention stage: 8 chunks of 16384 window-order rows (256 windows)
    for (int c = 0; c < 8; c++) {
        long base = (long)c * 16384;
        gather_cast<<<4096, 256, 0, stream>>>(x, xbfC, base);
        gemm_bt<0><<<dim3(6, 128), 256, 0, stream>>>(xbfC, qkvBt, qkvBias, qkvC, 16384, 768, 256);
        attn_kernel<<<2048, 64, 0, stream>>>(qkvC, bias16, ls, attnC);
        gemm_bt<0><<<dim3(2, 128), 256, 0, stream>>>(attnC, projBt, pb, projC, 16384, 256, 256);
        norm1_kernel<<<4096, 256, 0, stream>>>(projC, x, n1s, n1b, x1h, base);
    }

    // MLP stage: 8 chunks of 16384 orig-order rows
    for (int c = 0; c < 8; c++) {
        long base = (long)c * 16384;
        gemm_bt<1><<<dim3(8, 128), 256, 0, stream>>>(x1h + base * 256, fc1Bt, f1b, hC, 16384, 1024, 256);
        gemm_bt<0><<<dim3(2, 128), 256, 0, stream>>>(hC, fc2Bt, f2b, fc2C, 16384, 256, 1024);
        norm2_kernel<<<4096, 256, 0, stream>>>(fc2C, x1h, n2s, n2b, (float*)d_out, base);
    }
}

// Round 3
// 1060.675 us; speedup vs baseline: 1.3149x; 1.3149x over previous
//
#include <hip/hip_runtime.h>

typedef __bf16 bf16;
typedef __bf16 bf16x8 __attribute__((ext_vector_type(8)));
typedef __bf16 bf16x4 __attribute__((ext_vector_type(4)));
typedef float  f32x4  __attribute__((ext_vector_type(4)));

#define MFMA16(a, b, c) __builtin_amdgcn_mfma_f32_16x16x32_bf16(a, b, c, 0, 0, 0)

__device__ __forceinline__ void gload_lds16(const void* g, void* l) {
    __builtin_amdgcn_global_load_lds((const __attribute__((address_space(1))) void*)g,
                                     (__attribute__((address_space(3))) void*)l, 16, 0, 0);
}

// window-order row -> original-order row (inverse of roll(-4,-4)+partition)
__device__ __forceinline__ long win2orig(long r) {
    long b = r >> 12; int rem = (int)(r & 4095);
    int widx = rem >> 6, t = rem & 63;
    int rp = ((widx >> 3) << 3) + (t >> 3), cp = ((widx & 7) << 3) + (t & 7);
    int rr = (rp + 4) & 63, cc = (cp + 4) & 63;
    return (b << 12) + rr * 64 + cc;
}

// ---------------------------------------------------------------- GEMM
// C[M,N] = A[M,K] (bf16) * Bt[N,K]^T (bf16) + bias, optional gelu.
// m97 structure: 128x128 tile, BK=32, global_load_lds w=16, fragment-linear LDS.
template <int GELU>
__global__ __launch_bounds__(256) void gemm_bt(const bf16* __restrict__ A,
                                               const bf16* __restrict__ Bt,
                                               const float* __restrict__ bias,
                                               bf16* __restrict__ C,
                                               int M, int N, int K) {
    __shared__ bf16 As[4096];
    __shared__ bf16 Bs[4096];
    const int t = threadIdx.x;
    const int w = t >> 6, l = t & 63;
    const int l15 = l & 15, q4 = l >> 4;
    const int wm = w >> 1, wn = w & 1;
    const long row0 = (long)blockIdx.y * 128;
    const int col0 = blockIdx.x * 128;

    const bf16* aP = A + (row0 + w * 16 + l15) * (long)K + q4 * 8;
    const bf16* bP = Bt + (long)(col0 + w * 16 + l15) * K + q4 * 8;
    const long step64 = 64L * K;

    f32x4 acc[4][4];
#pragma unroll
    for (int i = 0; i < 4; i++)
#pragma unroll
        for (int j = 0; j < 4; j++)
#pragma unroll
            for (int r = 0; r < 4; r++) acc[i][j][r] = 0.f;

    const int KT = K >> 5;
    for (int kt = 0; kt < KT; ++kt) {
        __syncthreads();
        gload_lds16(aP,          &As[w * 512]);
        gload_lds16(aP + step64, &As[w * 512 + 2048]);
        gload_lds16(bP,          &Bs[w * 512]);
        gload_lds16(bP + step64, &Bs[w * 512 + 2048]);
        aP += 32; bP += 32;
        __syncthreads();
        bf16x8 af[4], bfv[4];
#pragma unroll
        for (int mi = 0; mi < 4; mi++) af[mi] = *(const bf16x8*)(&As[(wm * 4 + mi) * 512 + l * 8]);
#pragma unroll
        for (int nj = 0; nj < 4; nj++) bfv[nj] = *(const bf16x8*)(&Bs[(wn * 4 + nj) * 512 + l * 8]);
#pragma unroll
        for (int mi = 0; mi < 4; mi++)
#pragma unroll
            for (int nj = 0; nj < 4; nj++) acc[mi][nj] = MFMA16(af[mi], bfv[nj], acc[mi][nj]);
    }

    float cb[4];
#pragma unroll
    for (int nj = 0; nj < 4; nj++) cb[nj] = bias[col0 + wn * 64 + nj * 16 + l15];

#pragma unroll
    for (int mi = 0; mi < 4; mi++) {
#pragma unroll
        for (int reg = 0; reg < 4; reg++) {
            long r = row0 + wm * 64 + mi * 16 + q4 * 4 + reg;
            bf16* cpn = C + r * (long)N + col0 + wn * 64 + l15;
#pragma unroll
            for (int nj = 0; nj < 4; nj++) {
                float v = acc[mi][nj][reg] + cb[nj];
                if (GELU) {  // tanh gelu (jax.nn.gelu approximate=True)
                    float u = 0.7978845608028654f * (v + 0.044715f * v * v * v);
                    float e = __expf(2.f * u);
                    float th = 1.f - 2.f / (e + 1.f);
                    v = 0.5f * v * (1.f + th);
                }
                cpn[nj * 16] = (bf16)v;
            }
        }
    }
}

// ---------------------------------------------------------------- attention
// One wave per (window, head). qkv rows in window order.
__global__ __launch_bounds__(64) void attn_kernel(const bf16* __restrict__ qkv,
                                                  const float* __restrict__ bias16,
                                                  const float* __restrict__ logit_scale,
                                                  bf16* __restrict__ outp) {
    __shared__ bf16 P[64 * 72];
    __shared__ bf16 Vt[32 * 72];
    const int unit = blockIdx.x;
    const int w = unit >> 3, h = unit & 7;
    const int l = threadIdx.x;
    const int l15 = l & 15, q4 = l >> 4;
    const bf16* base = qkv + (long)w * 64 * 768;

    {  // stage V^T: lane l holds token l
        const bf16* vp = base + l * 768 + 512 + h * 32;
#pragma unroll
        for (int c = 0; c < 4; c++) {
            bf16x8 vv = *(const bf16x8*)(vp + c * 8);
#pragma unroll
            for (int j = 0; j < 8; j++) Vt[(c * 8 + j) * 72 + l] = vv[j];
        }
    }

    const float scale = __expf(fminf(logit_scale[h], 4.605170186f));

    bf16x8 qf[4], kf[4];
#pragma unroll
    for (int mi = 0; mi < 4; mi++) {  // l2-normalized Q fragments
        const bf16* p = base + (mi * 16 + l15) * 768 + h * 32 + q4 * 8;
        bf16x8 xv = *(const bf16x8*)p;
        float fv[8]; float ss = 0.f;
#pragma unroll
        for (int j = 0; j < 8; j++) { fv[j] = (float)xv[j]; ss += fv[j] * fv[j]; }
        ss += __shfl_xor(ss, 16); ss += __shfl_xor(ss, 32);
        float rs = rsqrtf(fmaxf(ss, 1e-12f));
#pragma unroll
        for (int j = 0; j < 8; j++) qf[mi][j] = (bf16)(fv[j] * rs);
    }
#pragma unroll
    for (int nj = 0; nj < 4; nj++) {  // l2-normalized K fragments
        const bf16* p = base + (nj * 16 + l15) * 768 + 256 + h * 32 + q4 * 8;
        bf16x8 xv = *(const bf16x8*)p;
        float fv[8]; float ss = 0.f;
#pragma unroll
        for (int j = 0; j < 8; j++) { fv[j] = (float)xv[j]; ss += fv[j] * fv[j]; }
        ss += __shfl_xor(ss, 16); ss += __shfl_xor(ss, 32);
        float rs = rsqrtf(fmaxf(ss, 1e-12f));
#pragma unroll
        for (int j = 0; j < 8; j++) kf[nj][j] = (bf16)(fv[j] * rs);
    }

    f32x4 acc[4][4];
#pragma unroll
    for (int i = 0; i < 4; i++)
#pragma unroll
        for (int j = 0; j < 4; j++)
#pragma unroll
            for (int r = 0; r < 4; r++) acc[i][j][r] = 0.f;
#pragma unroll
    for (int mi = 0; mi < 4; mi++)
#pragma unroll
        for (int nj = 0; nj < 4; nj++) acc[mi][nj] = MFMA16(qf[mi], kf[nj], acc[mi][nj]);

    // scale + CPB bias + shift mask
    const int widx = w & 63, wr = widx >> 3, wc = widx & 7;
    const bool edge = (wr == 7) || (wc == 7);
    int crid[4];
    if (edge) {
#pragma unroll
        for (int nj = 0; nj < 4; nj++) {
            int m = nj * 16 + l15;
            int R = wr * 8 + (m >> 3), Cc = wc * 8 + (m & 7);
            crid[nj] = ((R < 56) ? 0 : (R < 60 ? 1 : 2)) * 3 + ((Cc < 56) ? 0 : (Cc < 60 ? 1 : 2));
        }
    }
    const float* bh = bias16 + h * 4096;
#pragma unroll
    for (int mi = 0; mi < 4; mi++) {
#pragma unroll
        for (int reg = 0; reg < 4; reg++) {
            int n = mi * 16 + q4 * 4 + reg;
            const float* bp = bh + n * 64;
            int nrid = 0;
            if (edge) {
                int R = wr * 8 + (n >> 3), Cc = wc * 8 + (n & 7);
                nrid = ((R < 56) ? 0 : (R < 60 ? 1 : 2)) * 3 + ((Cc < 56) ? 0 : (Cc < 60 ? 1 : 2));
            }
#pragma unroll
            for (int nj = 0; nj < 4; nj++) {
                float v = acc[mi][nj][reg] * scale + bp[nj * 16 + l15];
                if (edge && nrid != crid[nj]) v -= 100.f;
                acc[mi][nj][reg] = v;
            }
        }
    }

    // row softmax (row = 16 lanes sharing q4, across 4 nj regs)
#pragma unroll
    for (int mi = 0; mi < 4; mi++) {
#pragma unroll
        for (int reg = 0; reg < 4; reg++) {
            float mx = fmaxf(fmaxf(acc[mi][0][reg], acc[mi][1][reg]),
                             fmaxf(acc[mi][2][reg], acc[mi][3][reg]));
            mx = fmaxf(mx, __shfl_xor(mx, 1));
            mx = fmaxf(mx, __shfl_xor(mx, 2));
            mx = fmaxf(mx, __shfl_xor(mx, 4));
            mx = fmaxf(mx, __shfl_xor(mx, 8));
            float s = 0.f;
#pragma unroll
            for (int nj = 0; nj < 4; nj++) {
                float e = __expf(acc[mi][nj][reg] - mx);
                acc[mi][nj][reg] = e; s += e;
            }
            s += __shfl_xor(s, 1); s += __shfl_xor(s, 2);
            s += __shfl_xor(s, 4); s += __shfl_xor(s, 8);
            float inv = 1.f / s;
            int n = mi * 16 + q4 * 4 + reg;
#pragma unroll
            for (int nj = 0; nj < 4; nj++)
                P[n * 72 + nj * 16 + l15] = (bf16)(acc[mi][nj][reg] * inv);
        }
    }
    __syncthreads();

    // O = P @ V  (K=64 in two 32-steps)
    f32x4 o[4][2];
#pragma unroll
    for (int i = 0; i < 4; i++)
#pragma unroll
        for (int j = 0; j < 2; j++)
#pragma unroll
            for (int r = 0; r < 4; r++) o[i][j][r] = 0.f;
#pragma unroll
    for (int ks = 0; ks < 2; ks++) {
        bf16x8 vf[2];
#pragma unroll
        for (int nj = 0; nj < 2; nj++) vf[nj] = *(const bf16x8*)(&Vt[(nj * 16 + l15) * 72 + ks * 32 + q4 * 8]);
#pragma unroll
        for (int mi = 0; mi < 4; mi++) {
            bf16x8 pf = *(const bf16x8*)(&P[(mi * 16 + l15) * 72 + ks * 32 + q4 * 8]);
#pragma unroll
            for (int nj = 0; nj < 2; nj++) o[mi][nj] = MFMA16(pf, vf[nj], o[mi][nj]);
        }
    }

    bf16* op = outp + (long)w * 64 * 256 + h * 32;
#pragma unroll
    for (int mi = 0; mi < 4; mi++)
#pragma unroll
        for (int reg = 0; reg < 4; reg++) {
            int tok = mi * 16 + q4 * 4 + reg;
#pragma unroll
            for (int nj = 0; nj < 2; nj++)
                op[tok * 256 + nj * 16 + l15] = (bf16)o[mi][nj][reg];
        }
}

// ---------------------------------------------------------------- norms
// norm1: rows in window order; scatter to orig order: x1 = x + LN(proj_out)
__global__ __launch_bounds__(256) void norm1_kernel(const bf16* __restrict__ pin,
                                                    const float* __restrict__ x,
                                                    const float* __restrict__ g,
                                                    const float* __restrict__ bb,
                                                    bf16* __restrict__ x1h) {
    const int tid = threadIdx.x;
    const int wid = tid >> 6, l = tid & 63;
    const long rl = (long)blockIdx.x * 4 + wid;
    bf16x4 v4 = *(const bf16x4*)(pin + rl * 256 + l * 4);
    float v[4]; float s = 0.f, sq = 0.f;
#pragma unroll
    for (int c = 0; c < 4; c++) { v[c] = (float)v4[c]; s += v[c]; sq += v[c] * v[c]; }
#pragma unroll
    for (int off = 1; off < 64; off <<= 1) { s += __shfl_xor(s, off); sq += __shfl_xor(sq, off); }
    float mu = s * 0.00390625f;
    float var = sq * 0.00390625f - mu * mu;
    float rstd = rsqrtf(var + 1e-6f);
    long orig = win2orig(rl);
    float4 xv = *(const float4*)(x + orig * 256 + l * 4);
    float4 gv = *(const float4*)(g + l * 4);
    float4 bv = *(const float4*)(bb + l * 4);
    bf16x4 oh;
    oh[0] = (bf16)(xv.x + ((v[0] - mu) * rstd * gv.x + bv.x));
    oh[1] = (bf16)(xv.y + ((v[1] - mu) * rstd * gv.y + bv.y));
    oh[2] = (bf16)(xv.z + ((v[2] - mu) * rstd * gv.z + bv.z));
    oh[3] = (bf16)(xv.w + ((v[3] - mu) * rstd * gv.w + bv.w));
    *(bf16x4*)(x1h + orig * 256 + l * 4) = oh;
}

// norm2: out = x1 + LN(fc2_out), all in orig order
__global__ __launch_bounds__(256) void norm2_kernel(const bf16* __restrict__ hin,
                                                    const bf16* __restrict__ x1h,
                                                    const float* __restrict__ g,
                                                    const float* __restrict__ bb,
                                                    float* __restrict__ outp) {
    const int tid = threadIdx.x;
    const int wid = tid >> 6, l = tid & 63;
    const long rl = (long)blockIdx.x * 4 + wid;
    bf16x4 v4 = *(const bf16x4*)(hin + rl * 256 + l * 4);
    float v[4]; float s = 0.f, sq = 0.f;
#pragma unroll
    for (int c = 0; c < 4; c++) { v[c] = (float)v4[c]; s += v[c]; sq += v[c] * v[c]; }
#pragma unroll
    for (int off = 1; off < 64; off <<= 1) { s += __shfl_xor(s, off); sq += __shfl_xor(sq, off); }
    float mu = s * 0.00390625f;
    float var = sq * 0.00390625f - mu * mu;
    float rstd = rsqrtf(var + 1e-6f);
    bf16x4 xv4 = *(const bf16x4*)(x1h + rl * 256 + l * 4);
    float4 gv = *(const float4*)(g + l * 4);
    float4 bv = *(const float4*)(bb + l * 4);
    float4 ov;
    ov.x = (float)xv4[0] + ((v[0] - mu) * rstd * gv.x + bv.x);
    ov.y = (float)xv4[1] + ((v[1] - mu) * rstd * gv.y + bv.y);
    ov.z = (float)xv4[2] + ((v[2] - mu) * rstd * gv.z + bv.z);
    ov.w = (float)xv4[3] + ((v[3] - mu) * rstd * gv.w + bv.w);
    *(float4*)(outp + rl * 256 + l * 4) = ov;
}

// ---------------------------------------------------------------- small prep
// gather rows (window order) from x (orig order, fp32), cast to bf16
__global__ __launch_bounds__(256) void gather_cast(const float* __restrict__ x,
                                                   bf16* __restrict__ out) {
    const int tid = threadIdx.x;
    const int wid = tid >> 6, l = tid & 63;
    const long rl = (long)blockIdx.x * 4 + wid;
    long orig = win2orig(rl);
    float4 v = *(const float4*)(x + orig * 256 + l * 4);
    bf16x4 o = {(bf16)v.x, (bf16)v.y, (bf16)v.z, (bf16)v.w};
    *(bf16x4*)(out + rl * 256 + l * 4) = o;
}

// out[N,K] = cast(in[K,N]^T)
__global__ void transpose_cast(const float* __restrict__ in, bf16* __restrict__ out, int K, int N) {
    int id = blockIdx.x * 256 + threadIdx.x;
    if (id < K * N) {
        int n = id / K, k = id - n * K;
        out[id] = (bf16)in[k * N + n];
    }
}

__global__ void build_qkv_bias(const float* __restrict__ qb, const float* __restrict__ vb,
                               float* __restrict__ out) {
    int i = blockIdx.x * 256 + threadIdx.x;
    if (i < 768) out[i] = (i < 256) ? qb[i] : ((i < 512) ? 0.f : vb[i - 512]);
}

__device__ __forceinline__ float cpcoord(int d) {
    float v = (float)d * (8.0f / 7.0f);
    float r = log2f(fabsf(v) + 1.0f) * (1.0f / 3.0f);
    return v < 0.f ? -r : r;
}

__global__ void cpb1(const float* __restrict__ w1, const float* __restrict__ b1,
                     const float* __restrict__ w2, float* __restrict__ tbl) {
    int a = threadIdx.x;
    if (a >= 225) return;
    int i = a / 15, j = a - i * 15;
    float t0 = cpcoord(i - 7), t1 = cpcoord(j - 7);
    float acc[8];
#pragma unroll
    for (int o = 0; o < 8; o++) acc[o] = 0.f;
    for (int jj = 0; jj < 512; jj++) {
        float hv = fmaf(t0, w1[jj], fmaf(t1, w1[512 + jj], b1[jj]));
        hv = fmaxf(hv, 0.f);
#pragma unroll
        for (int o = 0; o < 8; o++) acc[o] = fmaf(hv, w2[jj * 8 + o], acc[o]);
    }
#pragma unroll
    for (int o = 0; o < 8; o++) tbl[a * 8 + o] = acc[o];
}

__global__ void cpb2(const float* __restrict__ tbl, float* __restrict__ bias16) {
    int id = blockIdx.x * 256 + threadIdx.x;
    if (id >= 32768) return;
    int h = id >> 12, n = (id >> 6) & 63, m = id & 63;
    int r0 = (n >> 3) - (m >> 3) + 7;
    int r1 = (n & 7) - (m & 7) + 7;
    float v = tbl[(r0 * 15 + r1) * 8 + h];
    bias16[id] = 16.f / (1.f + __expf(-v));
}

// ---------------------------------------------------------------- launch
extern "C" void kernel_launch(void* const* d_in, const int* in_sizes, int n_in,
                              void* d_out, int out_size, void* d_ws, size_t ws_size,
                              hipStream_t stream) {
    const float* x   = (const float*)d_in[0];
    const float* qkvw= (const float*)d_in[1];
    const float* qb  = (const float*)d_in[2];
    const float* vb  = (const float*)d_in[3];
    const float* ls  = (const float*)d_in[4];
    const float* cw1 = (const float*)d_in[5];
    const float* cb1 = (const float*)d_in[6];
    const float* cw2 = (const float*)d_in[7];
    const float* pw  = (const float*)d_in[8];
    const float* pb  = (const float*)d_in[9];
    const float* n1s = (const float*)d_in[10];
    const float* n1b = (const float*)d_in[11];
    const float* n2s = (const float*)d_in[12];
    const float* n2b = (const float*)d_in[13];
    const float* f1w = (const float*)d_in[14];
    const float* f1b = (const float*)d_in[15];
    const float* f2w = (const float*)d_in[16];
    const float* f2b = (const float*)d_in[17];

    char* ws = (char*)d_ws;
    if (ws_size < 471859200UL) return;  // peak scratch = 450 MiB (harness gives 512 MiB)
    bf16*  qkvBt   = (bf16*)(ws + 0);
    bf16*  projBt  = (bf16*)(ws + 393216);
    bf16*  fc1Bt   = (bf16*)(ws + 524288);
    bf16*  fc2Bt   = (bf16*)(ws + 1048576);
    float* qkvBias = (float*)(ws + 1572864);
    float* cpbTbl  = (float*)(ws + 1575936);
    float* bias16  = (float*)(ws + 1583360);
    // big buffers (offsets in bytes from ws)
    bf16* xbf     = (bf16*)(ws + 2097152);     // 131072x256  (window order), 64 MiB
    bf16* qkvBuf  = (bf16*)(ws + 69206016);    // 131072x768, 192 MiB
    bf16* attnOut = (bf16*)(ws + 270532608);   // 131072x256, 64 MiB
    bf16* projOut = (bf16*)(ws + 337641472);   // 131072x256, 64 MiB
    bf16* x1h     = (bf16*)(ws + 404750336);   // 131072x256 (orig order), 64 MiB
    bf16* hBuf    = (bf16*)(ws + 2097152);     // 131072x1024, 256 MiB (aliases xbf+qkvBuf, dead)
    bf16* fc2Out  = (bf16*)(ws + 337641472);   // aliases projOut (dead after norm1)

    transpose_cast<<<768, 256, 0, stream>>>(qkvw, qkvBt, 256, 768);
    transpose_cast<<<256, 256, 0, stream>>>(pw, projBt, 256, 256);
    transpose_cast<<<1024, 256, 0, stream>>>(f1w, fc1Bt, 256, 1024);
    transpose_cast<<<1024, 256, 0, stream>>>(f2w, fc2Bt, 1024, 256);
    build_qkv_bias<<<3, 256, 0, stream>>>(qb, vb, qkvBias);
    cpb1<<<1, 256, 0, stream>>>(cw1, cb1, cw2, cpbTbl);
    cpb2<<<128, 256, 0, stream>>>(cpbTbl, bias16);

    gather_cast<<<32768, 256, 0, stream>>>(x, xbf);
    gemm_bt<0><<<dim3(6, 1024), 256, 0, stream>>>(xbf, qkvBt, qkvBias, qkvBuf, 131072, 768, 256);
    attn_kernel<<<16384, 64, 0, stream>>>(qkvBuf, bias16, ls, attnOut);
    gemm_bt<0><<<dim3(2, 1024), 256, 0, stream>>>(attnOut, projBt, pb, projOut, 131072, 256, 256);
    norm1_kernel<<<32768, 256, 0, stream>>>(projOut, x, n1s, n1b, x1h);
    gemm_bt<1><<<dim3(8, 1024), 256, 0, stream>>>(x1h, fc1Bt, f1b, hBuf, 131072, 1024, 256);
    gemm_bt<0><<<dim3(2, 1024), 256, 0, stream>>>(hBuf, fc2Bt, f2b, fc2Out, 131072, 256, 1024);
    norm2_kernel<<<32768, 256, 0, stream>>>(fc2Out, x1h, n2s, n2b, (float*)d_out);
}